// Round 1
// 120.706 us; speedup vs baseline: 1.0077x; 1.0077x over previous
//
#include <hip/hip_runtime.h>

// PatternAwareLoss — two-kernel structure, register-prefetch K-body.
// B=64, S=8192, L=24. Blocks of 256 threads handle 256 consecutive positions
// (1536 float4/int4 chunks, perfectly coalesced). 8192/256 = 32 blocks/row,
// so row boundaries align with block boundaries.
// R4 post-mortem: device-scope fence+counter finalize costs ~100 µs on CDNA4
// (non-coherent per-XCD L2) — a second 1-block launch is 20x cheaper.
// R5: halve LDS traffic by sign-encoding the chunk has-punct bit into the
// (strictly positive) BCE chunk sum; pad LDS layout to stride 9 so phase-2
// reads (9t+j, gcd(9,32)=1) are conflict-free (old 6t+j was 4-way); get the
// neighbor has-punct from a 257-byte array instead of re-reading 6 chunks;
// float2 partials (final kernel reads 16 KB not 32 KB, accumulates in double).
constexpr int Bdim = 64;
constexpr int S = 8192;
constexpr int L = 24;
constexpr int NPOS = Bdim * S;            // 524288
constexpr int POS_PER_BLK = 256;
constexpr int NBLK = NPOS / POS_PER_BLK;  // 2048
constexpr int BLK_PER_ROW = S / POS_PER_BLK; // 32
constexpr float BOOST = 1.2f;

__device__ __forceinline__ float bce(float x, float y) {
    // max(x,0) - x*y + log1p(exp(-|x|)) with HW transcendentals.
    // __logf arg in (1,2]: rel err ~1e-7; final-scalar impact ~1e-6 vs tol.
    float e = __expf(-fabsf(x));
    float l = __logf(1.0f + e);
    return fmaxf(x, 0.0f) - x * y + l;
}

__global__ __launch_bounds__(256) void pal_main(
    const float* __restrict__ logits,
    const int*   __restrict__ labels,
    const float* __restrict__ mask,
    float2*      __restrict__ partials)   // [NBLK]
{
    // position-major chunk sums, stride 9 (pad): index (c/6)*9 + c%6.
    // sign bit of each entry = "this chunk has any positive label".
    __shared__ float psum[POS_PER_BLK * 9];      // 9216 B
    __shared__ unsigned char hp_sh[POS_PER_BLK + 1]; // per-position has-punct + peek
    __shared__ float wl[4], wm[4];

    const int t = threadIdx.x;
    const size_t cbase = (size_t)blockIdx.x * 1536;   // 16B-chunk base

    // mask value needed in phase 2 — issue its load first so it's in flight
    float m = mask[(size_t)blockIdx.x * POS_PER_BLK + t];

    // ---- phase 1a: prefetch ALL chunks into registers (one vmcnt cluster,
    // not 6 dependent load->use stalls) ----
    float4 lg[6];
    int4   lb[6];
#pragma unroll
    for (int k = 0; k < 6; ++k) {
        const size_t c = cbase + (size_t)(t + 256 * k);
        lg[k] = ((const float4*)logits)[c];
        lb[k] = ((const int4*)labels)[c];
    }

    // t==0 peeks next block's first position (96 B) for the boundary boost;
    // forced 0 on the last block of a row (s==S-1 never boosts).
    if (t == 0) {
        int hn = 0;
        if ((blockIdx.x & (BLK_PER_ROW - 1)) != BLK_PER_ROW - 1) {
            const int4* nb = (const int4*)labels + cbase + 1536;
            int sn = 0;
#pragma unroll
            for (int j = 0; j < 6; ++j) { int4 v = nb[j]; sn += v.x + v.y + v.z + v.w; }
            hn = (sn > 0) ? 1 : 0;
        }
        hp_sh[POS_PER_BLK] = (unsigned char)hn;
    }

    // ---- phase 1b: per-chunk BCE sums, sign-encoded has-punct, to LDS ----
#pragma unroll
    for (int k = 0; k < 6; ++k) {
        float s = 0.0f;
        s += bce(lg[k].x, (float)lb[k].x);
        s += bce(lg[k].y, (float)lb[k].y);
        s += bce(lg[k].z, (float)lb[k].z);
        s += bce(lg[k].w, (float)lb[k].w);
        const int c = t + 256 * k;
        const int anyl = (lb[k].x + lb[k].y + lb[k].z + lb[k].w) > 0;
        // s > 0 strictly (log1p term), so the sign bit is free storage.
        psum[(c / 6) * 9 + (c % 6)] = anyl ? -s : s;
    }
    __syncthreads();

    // ---- phase 2: one position per thread — conflict-free stride-9 reads ----
    float ls = 0.0f;
    int hp = 0;
    const int rbase = 9 * t;
#pragma unroll
    for (int j = 0; j < 6; ++j) {
        const float v = psum[rbase + j];
        ls += fabsf(v);
        hp |= (v < 0.0f) ? 1 : 0;
    }
    hp_sh[t] = (unsigned char)hp;
    __syncthreads();

    const int hpn = hp_sh[t + 1];
    const float boost = (hp & hpn) ? BOOST : 1.0f;
    float contrib = ls * boost * m;

    // block reduction: wave shuffles, thread 0 folds 4 wave sums
#pragma unroll
    for (int off = 32; off > 0; off >>= 1) {
        contrib += __shfl_down(contrib, off, 64);
        m       += __shfl_down(m, off, 64);
    }
    if ((t & 63) == 0) { wl[t >> 6] = contrib; wm[t >> 6] = m; }
    __syncthreads();
    if (t == 0) {
        const float Ls = wl[0] + wl[1] + wl[2] + wl[3];
        const float Ms = wm[0] + wm[1] + wm[2] + wm[3];
        partials[blockIdx.x] = make_float2(Ls, Ms);
    }
}

__global__ __launch_bounds__(256) void pal_final(
    const float2* __restrict__ partials,
    float*        __restrict__ out)
{
    const int t = threadIdx.x;
    double l = 0.0, m = 0.0;
    for (int i = t; i < NBLK; i += 256) {
        const float2 p = partials[i];
        l += (double)p.x;
        m += (double)p.y;
    }
    __shared__ double sl[256], sm[256];
    sl[t] = l; sm[t] = m;
    __syncthreads();
    for (int off = 128; off > 0; off >>= 1) {
        if (t < off) { sl[t] += sl[t + off]; sm[t] += sm[t + off]; }
        __syncthreads();
    }
    if (t == 0) out[0] = (float)(sl[0] / sm[0]);
}

extern "C" void kernel_launch(void* const* d_in, const int* in_sizes, int n_in,
                              void* d_out, int out_size, void* d_ws, size_t ws_size,
                              hipStream_t stream) {
    const float* logits = (const float*)d_in[0];
    const int*   labels = (const int*)d_in[1];
    const float* mask   = (const float*)d_in[2];
    float*  out = (float*)d_out;
    float2* partials = (float2*)d_ws;   // NBLK float2 = 16 KB, fully written before read

    pal_main <<<NBLK, 256, 0, stream>>>(logits, labels, mask, partials);
    pal_final<<<1,    256, 0, stream>>>(partials, out);
}